// Round 5
// baseline (374.601 us; speedup 1.0000x reference)
//
#include <hip/hip_runtime.h>

// ---------------- problem constants ----------------
#define BATCH   4096
#define D1      200
#define W_IN    400          // 2*D1
#define OC      32
#define FW      9
#define W_OUT   392          // W_IN - FW + 1
#define FC_LEN  12544        // OC * W_OUT
#define FC1_LEN 288          // OC * FW
#define NDIM    400          // fc output dim
#define KDIM    FC_LEN
#define EPS     1e-5f

// ---------------- GEMM tiling ----------------
#define TM      128
#define TN      128
#define BK      32
#define SPLITK  4
#define KCHUNK  (KDIM / SPLITK)   // 3136
#define KITERS  (KCHUNK / BK)     // 98

typedef __attribute__((ext_vector_type(8))) __bf16 bf16x8;
typedef __attribute__((ext_vector_type(4))) float  f32x4;

// ============ kernel 1: gather + bn0 + hypernet k + conv + bn1 -> flat (bf16) ============
__global__ __launch_bounds__(256)
void prep_conv(const int* __restrict__ e1i, const int* __restrict__ ri,
               const int* __restrict__ e2i,
               const float* __restrict__ E, const float* __restrict__ R,
               const float* __restrict__ g0, const float* __restrict__ b0,
               const float* __restrict__ m0p, const float* __restrict__ v0,
               const float* __restrict__ fc1w, const float* __restrict__ fc1b,
               const float* __restrict__ g1, const float* __restrict__ b1,
               const float* __restrict__ m1, const float* __restrict__ v1,
               __bf16* __restrict__ flat)
{
    __shared__ float xs[W_IN];
    __shared__ float rs[D1];
    __shared__ float ks[FC1_LEN];

    const int b = blockIdx.x;
    const int t = threadIdx.x;
    const int i1 = e1i[b], i2 = e2i[b], ir = ri[b];

    const float s0 = g0[0] * rsqrtf(v0[0] + EPS);
    const float t0 = b0[0] - m0p[0] * s0;

    if (t < D1) {
        xs[t]      = E[(size_t)i1 * D1 + t] * s0 + t0;
        xs[D1 + t] = E[(size_t)i2 * D1 + t] * s0 + t0;
        rs[t]      = R[(size_t)ir * D1 + t];
    }
    __syncthreads();

    // k = r @ fc1_w.T + fc1_b   (row i of fc1_w = 200 floats = 800B, 16B aligned)
    for (int i = t; i < FC1_LEN; i += 256) {
        const float4* wrow = (const float4*)(fc1w + (size_t)i * D1);
        float acc = fc1b[i];
        #pragma unroll 10
        for (int c = 0; c < D1 / 4; ++c) {
            float4 wv = wrow[c];
            acc += rs[c * 4 + 0] * wv.x + rs[c * 4 + 1] * wv.y
                 + rs[c * 4 + 2] * wv.z + rs[c * 4 + 3] * wv.w;
        }
        ks[i] = acc;
    }
    __syncthreads();

    // conv (1x9, valid) + bn1 -> flat[b, oc*392 + w]  (bf16)
    const size_t obase = (size_t)b * FC_LEN;
    for (int oc = 0; oc < OC; ++oc) {
        float kv[FW];
        #pragma unroll
        for (int j = 0; j < FW; ++j) kv[j] = ks[oc * FW + j];
        const float inv = g1[oc] * rsqrtf(v1[oc] + EPS);
        const float mm = m1[oc], bb = b1[oc];
        for (int w = t; w < W_OUT; w += 256) {
            float a = 0.f;
            #pragma unroll
            for (int j = 0; j < FW; ++j) a += xs[w + j] * kv[j];
            flat[obase + oc * W_OUT + w] = (__bf16)((a - mm) * inv + bb);
        }
    }
}

// ============ kernel 2: h_partial = flat @ fc_w.T  (split-K, bf16 MFMA) ============
// A staged from bf16 flat; B staged from fp32 fc_w with in-register f32->bf16 cvt.
__global__ __launch_bounds__(256, 2)
void gemm_bt(const __bf16* __restrict__ Aflat, const float* __restrict__ Bwf,
             float* __restrict__ Hpart)
{
    __shared__ __align__(16) __bf16 Asm[TM * BK];   // 8 KB, row-major stride BK
    __shared__ __align__(16) __bf16 Bsm[TN * BK];   // 8 KB

    const int tid  = threadIdx.x;
    const int wave = tid >> 6;
    const int lane = tid & 63;
    const int m0 = blockIdx.x * TM;
    const int n0 = blockIdx.y * TN;
    const int kz = blockIdx.z;
    const size_t kbase = (size_t)kz * KCHUNK;

    // chunk ch in [0,512): row = ch>>2 (stride-BK row), sub = ch&3 (8-elt piece)
    const int row0 = tid >> 2, sub = tid & 3;
    const int row1 = 64 + row0;
    const __bf16* ag0 = Aflat + (size_t)(m0 + row0) * KDIM + kbase + sub * 8;
    const __bf16* ag1 = Aflat + (size_t)(m0 + row1) * KDIM + kbase + sub * 8;
    int rg0 = n0 + row0; if (rg0 > NDIM - 1) rg0 = NDIM - 1;   // clamp padded rows
    int rg1 = n0 + row1; if (rg1 > NDIM - 1) rg1 = NDIM - 1;
    const float* bg0 = Bwf + (size_t)rg0 * KDIM + kbase + sub * 8;
    const float* bg1 = Bwf + (size_t)rg1 * KDIM + kbase + sub * 8;
    __bf16* la0 = Asm + tid * 8;
    __bf16* la1 = Asm + 2048 + tid * 8;
    __bf16* lb0 = Bsm + tid * 8;
    __bf16* lb1 = Bsm + 2048 + tid * 8;

    const int quad = lane >> 4;
    const int mrow = lane & 15;
    const int wm = wave >> 1, wn = wave & 1;   // 2x2 wave grid, each wave 64x64
    const __bf16* afr[4];
    const __bf16* bfr[4];
    #pragma unroll
    for (int t = 0; t < 4; ++t) {
        afr[t] = Asm + (wm * 64 + t * 16 + mrow) * BK + quad * 8;
        bfr[t] = Bsm + (wn * 64 + t * 16 + mrow) * BK + quad * 8;
    }

    f32x4 acc[4][4];
    #pragma unroll
    for (int i = 0; i < 4; ++i)
        #pragma unroll
        for (int j = 0; j < 4; ++j) acc[i][j] = (f32x4){0.f, 0.f, 0.f, 0.f};

    for (int it = 0; it < KITERS; ++it) {
        bf16x8 ra0 = *(const bf16x8*)ag0;
        bf16x8 ra1 = *(const bf16x8*)ag1;
        float4 b0a = *(const float4*)bg0;
        float4 b0b = *(const float4*)(bg0 + 4);
        float4 b1a = *(const float4*)bg1;
        float4 b1b = *(const float4*)(bg1 + 4);
        ag0 += BK; ag1 += BK; bg0 += BK; bg1 += BK;

        bf16x8 rb0, rb1;
        rb0[0] = (__bf16)b0a.x; rb0[1] = (__bf16)b0a.y; rb0[2] = (__bf16)b0a.z; rb0[3] = (__bf16)b0a.w;
        rb0[4] = (__bf16)b0b.x; rb0[5] = (__bf16)b0b.y; rb0[6] = (__bf16)b0b.z; rb0[7] = (__bf16)b0b.w;
        rb1[0] = (__bf16)b1a.x; rb1[1] = (__bf16)b1a.y; rb1[2] = (__bf16)b1a.z; rb1[3] = (__bf16)b1a.w;
        rb1[4] = (__bf16)b1b.x; rb1[5] = (__bf16)b1b.y; rb1[6] = (__bf16)b1b.z; rb1[7] = (__bf16)b1b.w;

        __syncthreads();                 // prev iteration's LDS reads complete
        *(bf16x8*)la0 = ra0;
        *(bf16x8*)la1 = ra1;
        *(bf16x8*)lb0 = rb0;
        *(bf16x8*)lb1 = rb1;
        __syncthreads();                 // stores visible to all waves

        bf16x8 av[4], bv[4];
        #pragma unroll
        for (int t = 0; t < 4; ++t) av[t] = *(const bf16x8*)afr[t];
        #pragma unroll
        for (int t = 0; t < 4; ++t) bv[t] = *(const bf16x8*)bfr[t];
        #pragma unroll
        for (int i = 0; i < 4; ++i)
            #pragma unroll
            for (int j = 0; j < 4; ++j)
                acc[i][j] = __builtin_amdgcn_mfma_f32_16x16x32_bf16(av[i], bv[j], acc[i][j], 0, 0, 0);
    }

    // epilogue: C/D layout col=lane&15, row=(lane>>4)*4+reg  [m89-verified]
    float* Hp = Hpart + (size_t)kz * BATCH * NDIM;
    #pragma unroll
    for (int i = 0; i < 4; ++i) {
        const int rbase = m0 + wm * 64 + i * 16 + quad * 4;
        #pragma unroll
        for (int j = 0; j < 4; ++j) {
            const int col = n0 + wn * 64 + j * 16 + mrow;
            if (col < NDIM) {
                #pragma unroll
                for (int r = 0; r < 4; ++r)
                    Hp[(size_t)(rbase + r) * NDIM + col] = acc[i][j][r];
            }
        }
    }
}

// ============ kernel 3: sum partials + fc_b + bn2 + fc2 dot + tanh + bias ============
// OUTPUT IS float32 (reference returns jnp.float32; doc: "else float*").
// Value rounded through bf16 then widened so it matches a bf16-quantized ref too.
__global__ __launch_bounds__(256)
void finalize(const float* __restrict__ Hpart,
              const float* __restrict__ fcb,
              const float* __restrict__ g2, const float* __restrict__ b2,
              const float* __restrict__ m2, const float* __restrict__ v2,
              const float* __restrict__ fc2w, const float* __restrict__ fc2b,
              const float* __restrict__ bias,
              float* __restrict__ out)
{
    const int wave = threadIdx.x >> 6, lane = threadIdx.x & 63;
    const int e = blockIdx.x * 4 + wave;

    float acc = 0.f;
    for (int o = lane; o < NDIM; o += 64) {
        float hv = 0.f;
        #pragma unroll
        for (int z = 0; z < SPLITK; ++z)
            hv += Hpart[(size_t)z * BATCH * NDIM + (size_t)e * NDIM + o];
        hv += fcb[o];
        const float s2 = g2[o] * rsqrtf(v2[o] + EPS);
        const float hb = (hv - m2[o]) * s2 + b2[o];
        acc += hb * fc2w[o];
    }
    #pragma unroll
    for (int off = 32; off > 0; off >>= 1) acc += __shfl_down(acc, off);
    if (lane == 0) {
        float v = tanhf(acc + fc2b[0]) + bias[0];
        out[e] = (float)(__bf16)v;     // f32 store, bf16-grid value
    }
}

extern "C" void kernel_launch(void* const* d_in, const int* in_sizes, int n_in,
                              void* d_out, int out_size, void* d_ws, size_t ws_size,
                              hipStream_t stream)
{
    const int*   e1i  = (const int*)d_in[0];
    const int*   ri   = (const int*)d_in[1];
    const int*   e2i  = (const int*)d_in[2];
    const float* E    = (const float*)d_in[3];
    const float* R    = (const float*)d_in[4];
    const float* g0   = (const float*)d_in[5];
    const float* b0   = (const float*)d_in[6];
    const float* m0p  = (const float*)d_in[7];
    const float* v0   = (const float*)d_in[8];
    const float* fc1w = (const float*)d_in[9];
    const float* fc1b = (const float*)d_in[10];
    const float* g1   = (const float*)d_in[11];
    const float* b1   = (const float*)d_in[12];
    const float* m1   = (const float*)d_in[13];
    const float* v1   = (const float*)d_in[14];
    const float* fcw  = (const float*)d_in[15];
    const float* fcb  = (const float*)d_in[16];
    const float* g2   = (const float*)d_in[17];
    const float* b2   = (const float*)d_in[18];
    const float* m2   = (const float*)d_in[19];
    const float* v2   = (const float*)d_in[20];
    const float* fc2w = (const float*)d_in[21];
    const float* fc2b = (const float*)d_in[22];
    const float* bias = (const float*)d_in[23];

    // ws layout: flat bf16 [4096*12544] = 102,760,448 B | Hpart f32 [4*4096*400] = 26,214,400 B
    __bf16* flat  = (__bf16*)d_ws;
    float*  Hpart = (float*)((char*)d_ws + (size_t)BATCH * FC_LEN * 2);

    prep_conv<<<BATCH, 256, 0, stream>>>(e1i, ri, e2i, E, R, g0, b0, m0p, v0,
                                         fc1w, fc1b, g1, b1, m1, v1, flat);

    dim3 grid(BATCH / TM, (NDIM + TN - 1) / TN, SPLITK);   // 32 x 4 x 4
    gemm_bt<<<grid, 256, 0, stream>>>(flat, fcw, Hpart);

    finalize<<<BATCH / 4, 256, 0, stream>>>(Hpart, fcb, g2, b2, m2, v2, fc2w, fc2b, bias,
                                            (float*)d_out);
}

// Round 6
// 325.039 us; speedup vs baseline: 1.1525x; 1.1525x over previous
//
#include <hip/hip_runtime.h>

// ---------------- problem constants ----------------
#define BATCH   4096
#define D1      200
#define W_IN    400          // 2*D1
#define OC      32
#define FW      9
#define W_OUT   392          // W_IN - FW + 1
#define FC_LEN  12544        // OC * W_OUT
#define FC1_LEN 288          // OC * FW
#define NDIM    400          // fc output dim
#define KDIM    FC_LEN
#define EPS     1e-5f

// ---------------- GEMM tiling ----------------
#define TM      128
#define TN      128
#define BK      32

typedef __attribute__((ext_vector_type(8))) __bf16 bf16x8;
typedef __attribute__((ext_vector_type(4))) __bf16 bf16x4;
typedef __attribute__((ext_vector_type(4))) float  f32x4;

// async global->LDS, 16B per lane; LDS dest = wave-uniform base + lane*16  [m97]
__device__ __forceinline__ void gld_lds16(const void* g, void* l) {
    __builtin_amdgcn_global_load_lds(
        (const __attribute__((address_space(1))) void*)g,
        (__attribute__((address_space(3))) void*)l,
        16, 0, 0);
}

// ============ kernel 0: fc_w fp32 -> bf16 ============
__global__ __launch_bounds__(256)
void cvt_w(const float* __restrict__ src, __bf16* __restrict__ dst)
{
    const int i = (blockIdx.x * 256 + threadIdx.x) * 8;   // 2450 blocks cover 5,017,600 exactly
    float4 a = *(const float4*)(src + i);
    float4 b = *(const float4*)(src + i + 4);
    bf16x8 o;
    o[0] = (__bf16)a.x; o[1] = (__bf16)a.y; o[2] = (__bf16)a.z; o[3] = (__bf16)a.w;
    o[4] = (__bf16)b.x; o[5] = (__bf16)b.y; o[6] = (__bf16)b.z; o[7] = (__bf16)b.w;
    *(bf16x8*)(dst + i) = o;
}

// ============ kernel 1: gather + bn0 + hypernet k + conv + bn1 -> flat (bf16) ============
__global__ __launch_bounds__(256)
void prep_conv(const int* __restrict__ e1i, const int* __restrict__ ri,
               const int* __restrict__ e2i,
               const float* __restrict__ E, const float* __restrict__ R,
               const float* __restrict__ g0, const float* __restrict__ b0,
               const float* __restrict__ m0p, const float* __restrict__ v0,
               const float* __restrict__ fc1w, const float* __restrict__ fc1b,
               const float* __restrict__ g1, const float* __restrict__ b1,
               const float* __restrict__ m1, const float* __restrict__ v1,
               __bf16* __restrict__ flat)
{
    __shared__ float xs[W_IN];
    __shared__ float rs[D1];
    __shared__ float ks[FC1_LEN];
    __shared__ float cinv[OC], cm[OC], cb[OC];

    const int b = blockIdx.x;
    const int t = threadIdx.x;
    const int i1 = e1i[b], i2 = e2i[b], ir = ri[b];

    const float s0 = g0[0] * rsqrtf(v0[0] + EPS);
    const float t0 = b0[0] - m0p[0] * s0;

    if (t < D1) {
        xs[t]      = E[(size_t)i1 * D1 + t] * s0 + t0;
        xs[D1 + t] = E[(size_t)i2 * D1 + t] * s0 + t0;
        rs[t]      = R[(size_t)ir * D1 + t];
    }
    if (t >= 224 && t < 224 + OC) {          // bn1 constants (separate lane range)
        const int oc = t - 224;
        cinv[oc] = g1[oc] * rsqrtf(v1[oc] + EPS);
        cm[oc] = m1[oc]; cb[oc] = b1[oc];
    }
    __syncthreads();

    // k = r @ fc1_w.T + fc1_b   (row i of fc1_w = 200 floats, 16B aligned)
    for (int i = t; i < FC1_LEN; i += 256) {
        const float4* wrow = (const float4*)(fc1w + (size_t)i * D1);
        float acc = fc1b[i];
        #pragma unroll 10
        for (int c = 0; c < D1 / 4; ++c) {
            float4 wv = wrow[c];
            acc += rs[c * 4 + 0] * wv.x + rs[c * 4 + 1] * wv.y
                 + rs[c * 4 + 2] * wv.z + rs[c * 4 + 3] * wv.w;
        }
        ks[i] = acc;
    }
    __syncthreads();

    // conv (1x9, valid) + bn1, 4 outputs/thread, vector LDS reads + bf16x4 stores
    const size_t obase = (size_t)b * FC_LEN;
    for (int idx = t; idx < OC * (W_OUT / 4); idx += 256) {   // 3136
        const int oc = idx / (W_OUT / 4);
        const int w  = (idx - oc * (W_OUT / 4)) * 4;
        float4 xa = *(const float4*)(xs + w);
        float4 xb = *(const float4*)(xs + w + 4);
        float4 xc = *(const float4*)(xs + w + 8);
        float x[12] = {xa.x, xa.y, xa.z, xa.w, xb.x, xb.y, xb.z, xb.w, xc.x, xc.y, xc.z, xc.w};
        float a0 = 0.f, a1 = 0.f, a2 = 0.f, a3 = 0.f;
        #pragma unroll
        for (int j = 0; j < FW; ++j) {
            const float kj = ks[oc * FW + j];
            a0 += x[j] * kj; a1 += x[j + 1] * kj; a2 += x[j + 2] * kj; a3 += x[j + 3] * kj;
        }
        const float inv = cinv[oc], mm = cm[oc], bb = cb[oc];
        bf16x4 o;
        o[0] = (__bf16)((a0 - mm) * inv + bb);
        o[1] = (__bf16)((a1 - mm) * inv + bb);
        o[2] = (__bf16)((a2 - mm) * inv + bb);
        o[3] = (__bf16)((a3 - mm) * inv + bb);
        *(bf16x4*)(flat + obase + oc * W_OUT + w) = o;
    }
}

// ============ kernel 2a: async MFMA GEMM, XOR-swizzled LDS, templated split-K ============
// LDS layout: row-major 64B rows; within row, 16B piece p holds global k-piece p ^ ((row>>1)&3).
// Swizzle applied to the GLOBAL source address so global_load_lds stays lane-linear [m104].
template<int SK>
__global__ __launch_bounds__(256, 4)
void gemm_async(const __bf16* __restrict__ A, const __bf16* __restrict__ B,
                float* __restrict__ Hpart)
{
    constexpr int KCH = KDIM / SK;
    constexpr int KIT = KCH / BK;
    __shared__ __align__(16) __bf16 Asm[TM * BK];   // 8 KB
    __shared__ __align__(16) __bf16 Bsm[TN * BK];   // 8 KB

    const int tid  = threadIdx.x;
    const int wave = tid >> 6;
    const int lane = tid & 63;
    const int m0 = blockIdx.x * TM;
    const int n0 = blockIdx.y * TN;
    const size_t kbase = (size_t)blockIdx.z * KCH;

    // staging: chunk = c*256 + wave*64 + lane; row = chunk>>2, subslot = lane&3
    const __bf16* ag[2]; const __bf16* bg[2];
    __bf16* al[2]; __bf16* bl[2];
    #pragma unroll
    for (int c = 0; c < 2; ++c) {
        const int row = c * 64 + wave * 16 + (lane >> 2);
        const int sub = (lane & 3) ^ ((row >> 1) & 3);          // XOR swizzle
        ag[c] = A + (size_t)(m0 + row) * KDIM + kbase + sub * 8;
        int rg = n0 + row; if (rg > NDIM - 1) rg = NDIM - 1;    // clamp padded rows
        bg[c] = B + (size_t)rg * KDIM + kbase + sub * 8;
        al[c] = Asm + c * 2048 + wave * 512;                    // wave-uniform LDS base
        bl[c] = Bsm + c * 2048 + wave * 512;
    }

    const int quad = lane >> 4;
    const int mrow = lane & 15;
    const int wm = wave >> 1, wn = wave & 1;   // 2x2 wave grid, 64x64 per wave
    const __bf16* afr[4]; const __bf16* bfr[4];
    #pragma unroll
    for (int t = 0; t < 4; ++t) {
        const int ra = wm * 64 + t * 16 + mrow;
        const int rb = wn * 64 + t * 16 + mrow;
        afr[t] = Asm + ra * BK + ((quad ^ ((ra >> 1) & 3)) * 8);
        bfr[t] = Bsm + rb * BK + ((quad ^ ((rb >> 1) & 3)) * 8);
    }

    f32x4 acc[4][4];
    #pragma unroll
    for (int i = 0; i < 4; ++i)
        #pragma unroll
        for (int j = 0; j < 4; ++j) acc[i][j] = (f32x4){0.f, 0.f, 0.f, 0.f};

    for (int it = 0; it < KIT; ++it) {
        gld_lds16(ag[0], al[0]);
        gld_lds16(ag[1], al[1]);
        gld_lds16(bg[0], bl[0]);
        gld_lds16(bg[1], bl[1]);
        ag[0] += BK; ag[1] += BK; bg[0] += BK; bg[1] += BK;
        __syncthreads();   // drains vmcnt -> LDS valid

        bf16x8 av[4], bv[4];
        #pragma unroll
        for (int t = 0; t < 4; ++t) av[t] = *(const bf16x8*)afr[t];
        #pragma unroll
        for (int t = 0; t < 4; ++t) bv[t] = *(const bf16x8*)bfr[t];
        #pragma unroll
        for (int i = 0; i < 4; ++i)
            #pragma unroll
            for (int j = 0; j < 4; ++j)
                acc[i][j] = __builtin_amdgcn_mfma_f32_16x16x32_bf16(av[i], bv[j], acc[i][j], 0, 0, 0);
        __syncthreads();   // reads done before next stage overwrites
    }

    // epilogue: C/D layout col=lane&15, row=(lane>>4)*4+reg  [m89]
    float* Hp = Hpart + (size_t)blockIdx.z * BATCH * NDIM;
    #pragma unroll
    for (int i = 0; i < 4; ++i) {
        const int rbase = m0 + wm * 64 + i * 16 + quad * 4;
        #pragma unroll
        for (int j = 0; j < 4; ++j) {
            const int col = n0 + wn * 64 + j * 16 + mrow;
            if (col < NDIM) {
                #pragma unroll
                for (int r = 0; r < 4; ++r)
                    Hp[(size_t)(rbase + r) * NDIM + col] = acc[i][j][r];
            }
        }
    }
}

// ============ kernel 2b: proven R5 fallback (VGPR staging, fp32 B, split-K 4) ============
__global__ __launch_bounds__(256, 2)
void gemm_bt(const __bf16* __restrict__ Aflat, const float* __restrict__ Bwf,
             float* __restrict__ Hpart)
{
    __shared__ __align__(16) __bf16 Asm[TM * BK];
    __shared__ __align__(16) __bf16 Bsm[TN * BK];

    const int tid  = threadIdx.x;
    const int wave = tid >> 6;
    const int lane = tid & 63;
    const int m0 = blockIdx.x * TM;
    const int n0 = blockIdx.y * TN;
    const size_t kbase = (size_t)blockIdx.z * (KDIM / 4);

    const int row0 = tid >> 2, sub = tid & 3;
    const int row1 = 64 + row0;
    const __bf16* ag0 = Aflat + (size_t)(m0 + row0) * KDIM + kbase + sub * 8;
    const __bf16* ag1 = Aflat + (size_t)(m0 + row1) * KDIM + kbase + sub * 8;
    int rg0 = n0 + row0; if (rg0 > NDIM - 1) rg0 = NDIM - 1;
    int rg1 = n0 + row1; if (rg1 > NDIM - 1) rg1 = NDIM - 1;
    const float* bg0 = Bwf + (size_t)rg0 * KDIM + kbase + sub * 8;
    const float* bg1 = Bwf + (size_t)rg1 * KDIM + kbase + sub * 8;
    __bf16* la0 = Asm + tid * 8;
    __bf16* la1 = Asm + 2048 + tid * 8;
    __bf16* lb0 = Bsm + tid * 8;
    __bf16* lb1 = Bsm + 2048 + tid * 8;

    const int quad = lane >> 4;
    const int mrow = lane & 15;
    const int wm = wave >> 1, wn = wave & 1;
    const __bf16* afr[4]; const __bf16* bfr[4];
    #pragma unroll
    for (int t = 0; t < 4; ++t) {
        afr[t] = Asm + (wm * 64 + t * 16 + mrow) * BK + quad * 8;
        bfr[t] = Bsm + (wn * 64 + t * 16 + mrow) * BK + quad * 8;
    }

    f32x4 acc[4][4];
    #pragma unroll
    for (int i = 0; i < 4; ++i)
        #pragma unroll
        for (int j = 0; j < 4; ++j) acc[i][j] = (f32x4){0.f, 0.f, 0.f, 0.f};

    for (int it = 0; it < (KDIM / 4) / BK; ++it) {
        bf16x8 ra0 = *(const bf16x8*)ag0;
        bf16x8 ra1 = *(const bf16x8*)ag1;
        float4 b0a = *(const float4*)bg0;
        float4 b0b = *(const float4*)(bg0 + 4);
        float4 b1a = *(const float4*)bg1;
        float4 b1b = *(const float4*)(bg1 + 4);
        ag0 += BK; ag1 += BK; bg0 += BK; bg1 += BK;

        bf16x8 rb0, rb1;
        rb0[0] = (__bf16)b0a.x; rb0[1] = (__bf16)b0a.y; rb0[2] = (__bf16)b0a.z; rb0[3] = (__bf16)b0a.w;
        rb0[4] = (__bf16)b0b.x; rb0[5] = (__bf16)b0b.y; rb0[6] = (__bf16)b0b.z; rb0[7] = (__bf16)b0b.w;
        rb1[0] = (__bf16)b1a.x; rb1[1] = (__bf16)b1a.y; rb1[2] = (__bf16)b1a.z; rb1[3] = (__bf16)b1a.w;
        rb1[4] = (__bf16)b1b.x; rb1[5] = (__bf16)b1b.y; rb1[6] = (__bf16)b1b.z; rb1[7] = (__bf16)b1b.w;

        __syncthreads();
        *(bf16x8*)la0 = ra0;
        *(bf16x8*)la1 = ra1;
        *(bf16x8*)lb0 = rb0;
        *(bf16x8*)lb1 = rb1;
        __syncthreads();

        bf16x8 av[4], bv[4];
        #pragma unroll
        for (int t = 0; t < 4; ++t) av[t] = *(const bf16x8*)afr[t];
        #pragma unroll
        for (int t = 0; t < 4; ++t) bv[t] = *(const bf16x8*)bfr[t];
        #pragma unroll
        for (int i = 0; i < 4; ++i)
            #pragma unroll
            for (int j = 0; j < 4; ++j)
                acc[i][j] = __builtin_amdgcn_mfma_f32_16x16x32_bf16(av[i], bv[j], acc[i][j], 0, 0, 0);
    }

    float* Hp = Hpart + (size_t)blockIdx.z * BATCH * NDIM;
    #pragma unroll
    for (int i = 0; i < 4; ++i) {
        const int rbase = m0 + wm * 64 + i * 16 + quad * 4;
        #pragma unroll
        for (int j = 0; j < 4; ++j) {
            const int col = n0 + wn * 64 + j * 16 + mrow;
            if (col < NDIM) {
                #pragma unroll
                for (int r = 0; r < 4; ++r)
                    Hp[(size_t)(rbase + r) * NDIM + col] = acc[i][j][r];
            }
        }
    }
}

// ============ kernel 3: sum partials + fc_b + bn2 + fc2 dot + tanh + bias ============
__global__ __launch_bounds__(256)
void finalize(const float* __restrict__ Hpart, int sk,
              const float* __restrict__ fcb,
              const float* __restrict__ g2, const float* __restrict__ b2,
              const float* __restrict__ m2, const float* __restrict__ v2,
              const float* __restrict__ fc2w, const float* __restrict__ fc2b,
              const float* __restrict__ bias,
              float* __restrict__ out)
{
    const int wave = threadIdx.x >> 6, lane = threadIdx.x & 63;
    const int e = blockIdx.x * 4 + wave;

    float acc = 0.f;
    for (int o = lane; o < NDIM; o += 64) {
        float hv = 0.f;
        for (int z = 0; z < sk; ++z)
            hv += Hpart[(size_t)z * BATCH * NDIM + (size_t)e * NDIM + o];
        hv += fcb[o];
        const float s2 = g2[o] * rsqrtf(v2[o] + EPS);
        const float hb = (hv - m2[o]) * s2 + b2[o];
        acc += hb * fc2w[o];
    }
    #pragma unroll
    for (int off = 32; off > 0; off >>= 1) acc += __shfl_down(acc, off);
    if (lane == 0)
        out[e] = tanhf(acc + fc2b[0]) + bias[0];   // raw f32 (ref=np fp32)
}

extern "C" void kernel_launch(void* const* d_in, const int* in_sizes, int n_in,
                              void* d_out, int out_size, void* d_ws, size_t ws_size,
                              hipStream_t stream)
{
    const int*   e1i  = (const int*)d_in[0];
    const int*   ri   = (const int*)d_in[1];
    const int*   e2i  = (const int*)d_in[2];
    const float* E    = (const float*)d_in[3];
    const float* R    = (const float*)d_in[4];
    const float* g0   = (const float*)d_in[5];
    const float* b0   = (const float*)d_in[6];
    const float* m0p  = (const float*)d_in[7];
    const float* v0   = (const float*)d_in[8];
    const float* fc1w = (const float*)d_in[9];
    const float* fc1b = (const float*)d_in[10];
    const float* g1   = (const float*)d_in[11];
    const float* b1   = (const float*)d_in[12];
    const float* m1   = (const float*)d_in[13];
    const float* v1   = (const float*)d_in[14];
    const float* fcw  = (const float*)d_in[15];
    const float* fcb  = (const float*)d_in[16];
    const float* g2   = (const float*)d_in[17];
    const float* b2   = (const float*)d_in[18];
    const float* m2   = (const float*)d_in[19];
    const float* v2   = (const float*)d_in[20];
    const float* fc2w = (const float*)d_in[21];
    const float* fc2b = (const float*)d_in[22];
    const float* bias = (const float*)d_in[23];

    const size_t flat_b = (size_t)BATCH * FC_LEN * 2;   // 102,760,448
    const size_t bw_b   = (size_t)NDIM * KDIM * 2;      //  10,035,200
    const size_t hp_b1  = (size_t)BATCH * NDIM * 4;     //   6,553,600 per split
    const size_t need8  = flat_b + bw_b + 8 * hp_b1;    // 165,224,448
    const size_t need4  = flat_b + bw_b + 4 * hp_b1;    // 139,010,048

    __bf16* flat = (__bf16*)d_ws;

    prep_conv<<<BATCH, 256, 0, stream>>>(e1i, ri, e2i, E, R, g0, b0, m0p, v0,
                                         fc1w, fc1b, g1, b1, m1, v1, flat);

    if (ws_size >= need4) {
        // async path: Bw bf16 after flat, Hpart after Bw
        __bf16* Bw    = (__bf16*)((char*)d_ws + flat_b);
        float*  Hpart = (float*)((char*)d_ws + flat_b + bw_b);
        const int sk  = (ws_size >= need8) ? 8 : 4;

        cvt_w<<<(NDIM * KDIM) / 2048, 256, 0, stream>>>(fcw, Bw);

        dim3 grid(BATCH / TM, (NDIM + TN - 1) / TN, sk);
        if (sk == 8) gemm_async<8><<<grid, 256, 0, stream>>>(flat, Bw, Hpart);
        else         gemm_async<4><<<grid, 256, 0, stream>>>(flat, Bw, Hpart);

        finalize<<<BATCH / 4, 256, 0, stream>>>(Hpart, sk, fcb, g2, b2, m2, v2,
                                                fc2w, fc2b, bias, (float*)d_out);
    } else {
        // proven fallback (R5): no Bw, split-K 4
        float* Hpart = (float*)((char*)d_ws + flat_b);
        dim3 grid(BATCH / TM, (NDIM + TN - 1) / TN, 4);
        gemm_bt<<<grid, 256, 0, stream>>>(flat, fcw, Hpart);
        finalize<<<BATCH / 4, 256, 0, stream>>>(Hpart, 4, fcb, g2, b2, m2, v2,
                                                fc2w, fc2b, bias, (float*)d_out);
    }
}

// Round 7
// 297.092 us; speedup vs baseline: 1.2609x; 1.0941x over previous
//
#include <hip/hip_runtime.h>

// ---------------- problem constants ----------------
#define BATCH   4096
#define N_REL   500
#define D1      200
#define W_IN    400          // 2*D1
#define OC      32
#define FW      9
#define W_OUT   392          // W_IN - FW + 1
#define FC_LEN  12544        // OC * W_OUT
#define FC1_LEN 288          // OC * FW
#define NDIM    400          // fc output dim
#define KDIM    FC_LEN
#define EPS     1e-5f

// ---------------- GEMM tiling ----------------
#define TM      128
#define TN      128
#define BK      32

typedef __attribute__((ext_vector_type(8))) __bf16 bf16x8;
typedef __attribute__((ext_vector_type(4))) __bf16 bf16x4;
typedef __attribute__((ext_vector_type(4))) float  f32x4;

// async global->LDS, 16B per lane; LDS dest = wave-uniform base + lane*16  [m97]
__device__ __forceinline__ void gld_lds16(const void* g, void* l) {
    __builtin_amdgcn_global_load_lds(
        (const __attribute__((address_space(1))) void*)g,
        (__attribute__((address_space(3))) void*)l,
        16, 0, 0);
}

// ============ kernel 0: fc_w fp32 -> bf16 ============
__global__ __launch_bounds__(256)
void cvt_w(const float* __restrict__ src, __bf16* __restrict__ dst)
{
    const int i = (blockIdx.x * 256 + threadIdx.x) * 8;   // 2450 blocks cover 5,017,600 exactly
    float4 a = *(const float4*)(src + i);
    float4 b = *(const float4*)(src + i + 4);
    bf16x8 o;
    o[0] = (__bf16)a.x; o[1] = (__bf16)a.y; o[2] = (__bf16)a.z; o[3] = (__bf16)a.w;
    o[4] = (__bf16)b.x; o[5] = (__bf16)b.y; o[6] = (__bf16)b.z; o[7] = (__bf16)b.w;
    *(bf16x8*)(dst + i) = o;
}

// ============ kernel A: per-relation hypernet filters, bn1 scale folded ============
// KR[rel][i] = (R[rel]·fc1_w[i] + fc1_b[i]) * inv1[i/9],  i < 288
__global__ __launch_bounds__(320)
void krel(const float* __restrict__ R, const float* __restrict__ fc1w,
          const float* __restrict__ fc1b,
          const float* __restrict__ g1, const float* __restrict__ v1,
          float* __restrict__ KR)
{
    __shared__ float rs[D1];
    const int rel = blockIdx.x;
    const int t = threadIdx.x;
    if (t < D1) rs[t] = R[(size_t)rel * D1 + t];
    __syncthreads();
    if (t < FC1_LEN) {
        const float4* wrow = (const float4*)(fc1w + (size_t)t * D1);
        float acc = fc1b[t];
        #pragma unroll 10
        for (int c = 0; c < D1 / 4; ++c) {
            float4 wv = wrow[c];
            acc += rs[c * 4 + 0] * wv.x + rs[c * 4 + 1] * wv.y
                 + rs[c * 4 + 2] * wv.z + rs[c * 4 + 3] * wv.w;
        }
        const int oc = t / FW;
        KR[(size_t)rel * FC1_LEN + t] = acc * (g1[oc] * rsqrtf(v1[oc] + EPS));
    }
}

// ============ kernel B: gather + bn0 + conv(1x9) + bn1 -> flat (bf16) ============
// flat[b, oc*392 + w] = sum_j xs[w+j] * ks[oc*9+j] + cadd[oc]
__global__ __launch_bounds__(256)
void conv_flat(const int* __restrict__ e1i, const int* __restrict__ ri,
               const int* __restrict__ e2i,
               const float* __restrict__ E, const float* __restrict__ KR,
               const float* __restrict__ g0, const float* __restrict__ b0,
               const float* __restrict__ m0p, const float* __restrict__ v0,
               const float* __restrict__ g1, const float* __restrict__ b1,
               const float* __restrict__ m1, const float* __restrict__ v1,
               __bf16* __restrict__ flat)
{
    __shared__ float xs[W_IN];
    __shared__ float ks[FC1_LEN];
    __shared__ float cadd[OC];

    const int b = blockIdx.x;
    const int t = threadIdx.x;
    const int i1 = e1i[b], i2 = e2i[b], ir = ri[b];

    const float s0 = g0[0] * rsqrtf(v0[0] + EPS);
    const float t0 = b0[0] - m0p[0] * s0;

    if (t < D1) {
        xs[t]      = E[(size_t)i1 * D1 + t] * s0 + t0;
        xs[D1 + t] = E[(size_t)i2 * D1 + t] * s0 + t0;
    }
    if (t >= 224 && t < 224 + OC) {
        const int oc = t - 224;
        cadd[oc] = b1[oc] - m1[oc] * (g1[oc] * rsqrtf(v1[oc] + EPS));
    }
    for (int i = t; i < FC1_LEN; i += 256)
        ks[i] = KR[(size_t)ir * FC1_LEN + i];
    __syncthreads();

    // units: 32 oc x 49 groups of 8 outputs (392 = 49*8 exact)
    const size_t obase = (size_t)b * FC_LEN;
    for (int u = t; u < OC * 49; u += 256) {        // 1568 units, 6.125/thread
        const int oc = u / 49;
        const int w  = (u - oc * 49) * 8;
        float4 xa = *(const float4*)(xs + w);
        float4 xb = *(const float4*)(xs + w + 4);
        float4 xc = *(const float4*)(xs + w + 8);
        float4 xd = *(const float4*)(xs + w + 12);
        float x[16] = {xa.x, xa.y, xa.z, xa.w, xb.x, xb.y, xb.z, xb.w,
                       xc.x, xc.y, xc.z, xc.w, xd.x, xd.y, xd.z, xd.w};
        const float c0 = cadd[oc];
        float a[8] = {c0, c0, c0, c0, c0, c0, c0, c0};
        #pragma unroll
        for (int j = 0; j < FW; ++j) {
            const float kj = ks[oc * FW + j];
            #pragma unroll
            for (int p = 0; p < 8; ++p) a[p] += x[j + p] * kj;
        }
        bf16x8 o;
        #pragma unroll
        for (int p = 0; p < 8; ++p) o[p] = (__bf16)a[p];
        *(bf16x8*)(flat + obase + oc * W_OUT + w) = o;   // 16B aligned (w%8==0)
    }
}

// ============ kernel 2a: async MFMA GEMM, XOR-swizzled LDS, templated split-K ============
template<int SK>
__global__ __launch_bounds__(256, 4)
void gemm_async(const __bf16* __restrict__ A, const __bf16* __restrict__ B,
                float* __restrict__ Hpart)
{
    constexpr int KCH = KDIM / SK;
    constexpr int KIT = KCH / BK;
    __shared__ __align__(16) __bf16 Asm[TM * BK];   // 8 KB
    __shared__ __align__(16) __bf16 Bsm[TN * BK];   // 8 KB

    const int tid  = threadIdx.x;
    const int wave = tid >> 6;
    const int lane = tid & 63;
    const int m0 = blockIdx.x * TM;
    const int n0 = blockIdx.y * TN;
    const size_t kbase = (size_t)blockIdx.z * KCH;

    const __bf16* ag[2]; const __bf16* bg[2];
    __bf16* al[2]; __bf16* bl[2];
    #pragma unroll
    for (int c = 0; c < 2; ++c) {
        const int row = c * 64 + wave * 16 + (lane >> 2);
        const int sub = (lane & 3) ^ ((row >> 1) & 3);          // XOR swizzle
        ag[c] = A + (size_t)(m0 + row) * KDIM + kbase + sub * 8;
        int rg = n0 + row; if (rg > NDIM - 1) rg = NDIM - 1;    // clamp padded rows
        bg[c] = B + (size_t)rg * KDIM + kbase + sub * 8;
        al[c] = Asm + c * 2048 + wave * 512;                    // wave-uniform LDS base
        bl[c] = Bsm + c * 2048 + wave * 512;
    }

    const int quad = lane >> 4;
    const int mrow = lane & 15;
    const int wm = wave >> 1, wn = wave & 1;   // 2x2 wave grid, 64x64 per wave
    const __bf16* afr[4]; const __bf16* bfr[4];
    #pragma unroll
    for (int t = 0; t < 4; ++t) {
        const int ra = wm * 64 + t * 16 + mrow;
        const int rb = wn * 64 + t * 16 + mrow;
        afr[t] = Asm + ra * BK + ((quad ^ ((ra >> 1) & 3)) * 8);
        bfr[t] = Bsm + rb * BK + ((quad ^ ((rb >> 1) & 3)) * 8);
    }

    f32x4 acc[4][4];
    #pragma unroll
    for (int i = 0; i < 4; ++i)
        #pragma unroll
        for (int j = 0; j < 4; ++j) acc[i][j] = (f32x4){0.f, 0.f, 0.f, 0.f};

    for (int it = 0; it < KIT; ++it) {
        gld_lds16(ag[0], al[0]);
        gld_lds16(ag[1], al[1]);
        gld_lds16(bg[0], bl[0]);
        gld_lds16(bg[1], bl[1]);
        ag[0] += BK; ag[1] += BK; bg[0] += BK; bg[1] += BK;
        __syncthreads();

        bf16x8 av[4], bv[4];
        #pragma unroll
        for (int t = 0; t < 4; ++t) av[t] = *(const bf16x8*)afr[t];
        #pragma unroll
        for (int t = 0; t < 4; ++t) bv[t] = *(const bf16x8*)bfr[t];
        #pragma unroll
        for (int i = 0; i < 4; ++i)
            #pragma unroll
            for (int j = 0; j < 4; ++j)
                acc[i][j] = __builtin_amdgcn_mfma_f32_16x16x32_bf16(av[i], bv[j], acc[i][j], 0, 0, 0);
        __syncthreads();
    }

    float* Hp = Hpart + (size_t)blockIdx.z * BATCH * NDIM;
    #pragma unroll
    for (int i = 0; i < 4; ++i) {
        const int rbase = m0 + wm * 64 + i * 16 + quad * 4;
        #pragma unroll
        for (int j = 0; j < 4; ++j) {
            const int col = n0 + wn * 64 + j * 16 + mrow;
            if (col < NDIM) {
                #pragma unroll
                for (int r = 0; r < 4; ++r)
                    Hp[(size_t)(rbase + r) * NDIM + col] = acc[i][j][r];
            }
        }
    }
}

// ============ kernel 2b: proven fallback (VGPR staging, fp32 B, split-K 4) ============
__global__ __launch_bounds__(256, 2)
void gemm_bt(const __bf16* __restrict__ Aflat, const float* __restrict__ Bwf,
             float* __restrict__ Hpart)
{
    __shared__ __align__(16) __bf16 Asm[TM * BK];
    __shared__ __align__(16) __bf16 Bsm[TN * BK];

    const int tid  = threadIdx.x;
    const int wave = tid >> 6;
    const int lane = tid & 63;
    const int m0 = blockIdx.x * TM;
    const int n0 = blockIdx.y * TN;
    const size_t kbase = (size_t)blockIdx.z * (KDIM / 4);

    const int row0 = tid >> 2, sub = tid & 3;
    const int row1 = 64 + row0;
    const __bf16* ag0 = Aflat + (size_t)(m0 + row0) * KDIM + kbase + sub * 8;
    const __bf16* ag1 = Aflat + (size_t)(m0 + row1) * KDIM + kbase + sub * 8;
    int rg0 = n0 + row0; if (rg0 > NDIM - 1) rg0 = NDIM - 1;
    int rg1 = n0 + row1; if (rg1 > NDIM - 1) rg1 = NDIM - 1;
    const float* bg0 = Bwf + (size_t)rg0 * KDIM + kbase + sub * 8;
    const float* bg1 = Bwf + (size_t)rg1 * KDIM + kbase + sub * 8;
    __bf16* la0 = Asm + tid * 8;
    __bf16* la1 = Asm + 2048 + tid * 8;
    __bf16* lb0 = Bsm + tid * 8;
    __bf16* lb1 = Bsm + 2048 + tid * 8;

    const int quad = lane >> 4;
    const int mrow = lane & 15;
    const int wm = wave >> 1, wn = wave & 1;
    const __bf16* afr[4]; const __bf16* bfr[4];
    #pragma unroll
    for (int t = 0; t < 4; ++t) {
        afr[t] = Asm + (wm * 64 + t * 16 + mrow) * BK + quad * 8;
        bfr[t] = Bsm + (wn * 64 + t * 16 + mrow) * BK + quad * 8;
    }

    f32x4 acc[4][4];
    #pragma unroll
    for (int i = 0; i < 4; ++i)
        #pragma unroll
        for (int j = 0; j < 4; ++j) acc[i][j] = (f32x4){0.f, 0.f, 0.f, 0.f};

    for (int it = 0; it < (KDIM / 4) / BK; ++it) {
        bf16x8 ra0 = *(const bf16x8*)ag0;
        bf16x8 ra1 = *(const bf16x8*)ag1;
        float4 b0a = *(const float4*)bg0;
        float4 b0b = *(const float4*)(bg0 + 4);
        float4 b1a = *(const float4*)bg1;
        float4 b1b = *(const float4*)(bg1 + 4);
        ag0 += BK; ag1 += BK; bg0 += BK; bg1 += BK;

        bf16x8 rb0, rb1;
        rb0[0] = (__bf16)b0a.x; rb0[1] = (__bf16)b0a.y; rb0[2] = (__bf16)b0a.z; rb0[3] = (__bf16)b0a.w;
        rb0[4] = (__bf16)b0b.x; rb0[5] = (__bf16)b0b.y; rb0[6] = (__bf16)b0b.z; rb0[7] = (__bf16)b0b.w;
        rb1[0] = (__bf16)b1a.x; rb1[1] = (__bf16)b1a.y; rb1[2] = (__bf16)b1a.z; rb1[3] = (__bf16)b1a.w;
        rb1[4] = (__bf16)b1b.x; rb1[5] = (__bf16)b1b.y; rb1[6] = (__bf16)b1b.z; rb1[7] = (__bf16)b1b.w;

        __syncthreads();
        *(bf16x8*)la0 = ra0;
        *(bf16x8*)la1 = ra1;
        *(bf16x8*)lb0 = rb0;
        *(bf16x8*)lb1 = rb1;
        __syncthreads();

        bf16x8 av[4], bv[4];
        #pragma unroll
        for (int t = 0; t < 4; ++t) av[t] = *(const bf16x8*)afr[t];
        #pragma unroll
        for (int t = 0; t < 4; ++t) bv[t] = *(const bf16x8*)bfr[t];
        #pragma unroll
        for (int i = 0; i < 4; ++i)
            #pragma unroll
            for (int j = 0; j < 4; ++j)
                acc[i][j] = __builtin_amdgcn_mfma_f32_16x16x32_bf16(av[i], bv[j], acc[i][j], 0, 0, 0);
    }

    float* Hp = Hpart + (size_t)blockIdx.z * BATCH * NDIM;
    #pragma unroll
    for (int i = 0; i < 4; ++i) {
        const int rbase = m0 + wm * 64 + i * 16 + quad * 4;
        #pragma unroll
        for (int j = 0; j < 4; ++j) {
            const int col = n0 + wn * 64 + j * 16 + mrow;
            if (col < NDIM) {
                #pragma unroll
                for (int r = 0; r < 4; ++r)
                    Hp[(size_t)(rbase + r) * NDIM + col] = acc[i][j][r];
            }
        }
    }
}

// ============ kernel 3: sum partials + fc_b + bn2 + fc2 dot + tanh + bias ============
__global__ __launch_bounds__(256)
void finalize(const float* __restrict__ Hpart, int sk,
              const float* __restrict__ fcb,
              const float* __restrict__ g2, const float* __restrict__ b2,
              const float* __restrict__ m2, const float* __restrict__ v2,
              const float* __restrict__ fc2w, const float* __restrict__ fc2b,
              const float* __restrict__ bias,
              float* __restrict__ out)
{
    const int wave = threadIdx.x >> 6, lane = threadIdx.x & 63;
    const int e = blockIdx.x * 4 + wave;

    float acc = 0.f;
    for (int o = lane; o < NDIM; o += 64) {
        float hv = 0.f;
        for (int z = 0; z < sk; ++z)
            hv += Hpart[(size_t)z * BATCH * NDIM + (size_t)e * NDIM + o];
        hv += fcb[o];
        const float s2 = g2[o] * rsqrtf(v2[o] + EPS);
        const float hb = (hv - m2[o]) * s2 + b2[o];
        acc += hb * fc2w[o];
    }
    #pragma unroll
    for (int off = 32; off > 0; off >>= 1) acc += __shfl_down(acc, off);
    if (lane == 0)
        out[e] = tanhf(acc + fc2b[0]) + bias[0];
}

extern "C" void kernel_launch(void* const* d_in, const int* in_sizes, int n_in,
                              void* d_out, int out_size, void* d_ws, size_t ws_size,
                              hipStream_t stream)
{
    const int*   e1i  = (const int*)d_in[0];
    const int*   ri   = (const int*)d_in[1];
    const int*   e2i  = (const int*)d_in[2];
    const float* E    = (const float*)d_in[3];
    const float* R    = (const float*)d_in[4];
    const float* g0   = (const float*)d_in[5];
    const float* b0   = (const float*)d_in[6];
    const float* m0p  = (const float*)d_in[7];
    const float* v0   = (const float*)d_in[8];
    const float* fc1w = (const float*)d_in[9];
    const float* fc1b = (const float*)d_in[10];
    const float* g1   = (const float*)d_in[11];
    const float* b1   = (const float*)d_in[12];
    const float* m1   = (const float*)d_in[13];
    const float* v1   = (const float*)d_in[14];
    const float* fcw  = (const float*)d_in[15];
    const float* fcb  = (const float*)d_in[16];
    const float* g2   = (const float*)d_in[17];
    const float* b2   = (const float*)d_in[18];
    const float* m2   = (const float*)d_in[19];
    const float* v2   = (const float*)d_in[20];
    const float* fc2w = (const float*)d_in[21];
    const float* fc2b = (const float*)d_in[22];
    const float* bias = (const float*)d_in[23];

    const size_t flat_b = (size_t)BATCH * FC_LEN * 2;   // 102,760,448
    const size_t bw_b   = (size_t)NDIM * KDIM * 2;      //  10,035,200
    const size_t hp_b1  = (size_t)BATCH * NDIM * 4;     //   6,553,600 per split
    const size_t kr_b   = (size_t)N_REL * FC1_LEN * 4;  //     576,000
    const size_t need8  = flat_b + bw_b + 8 * hp_b1 + kr_b;   // ~165.8 MB
    const size_t need4  = flat_b + bw_b + 4 * hp_b1 + kr_b;   // ~139.6 MB

    __bf16* flat = (__bf16*)d_ws;

    if (ws_size >= need4) {
        __bf16* Bw    = (__bf16*)((char*)d_ws + flat_b);
        float*  Hpart = (float*)((char*)d_ws + flat_b + bw_b);
        const int sk  = (ws_size >= need8) ? 8 : 4;
        float*  KR    = (float*)((char*)d_ws + flat_b + bw_b + (size_t)sk * hp_b1);

        krel<<<N_REL, 320, 0, stream>>>(R, fc1w, fc1b, g1, v1, KR);
        conv_flat<<<BATCH, 256, 0, stream>>>(e1i, ri, e2i, E, KR, g0, b0, m0p, v0,
                                             g1, b1, m1, v1, flat);
        cvt_w<<<(NDIM * KDIM) / 2048, 256, 0, stream>>>(fcw, Bw);

        dim3 grid(BATCH / TM, (NDIM + TN - 1) / TN, sk);
        if (sk == 8) gemm_async<8><<<grid, 256, 0, stream>>>(flat, Bw, Hpart);
        else         gemm_async<4><<<grid, 256, 0, stream>>>(flat, Bw, Hpart);

        finalize<<<BATCH / 4, 256, 0, stream>>>(Hpart, sk, fcb, g2, b2, m2, v2,
                                                fc2w, fc2b, bias, (float*)d_out);
    } else {
        // fallback: no Bw; split-K 4; KR after Hpart
        float*  Hpart = (float*)((char*)d_ws + flat_b);
        float*  KR    = (float*)((char*)d_ws + flat_b + 4 * hp_b1);

        krel<<<N_REL, 320, 0, stream>>>(R, fc1w, fc1b, g1, v1, KR);
        conv_flat<<<BATCH, 256, 0, stream>>>(e1i, ri, e2i, E, KR, g0, b0, m0p, v0,
                                             g1, b1, m1, v1, flat);

        dim3 grid(BATCH / TM, (NDIM + TN - 1) / TN, 4);
        gemm_bt<<<grid, 256, 0, stream>>>(flat, fcw, Hpart);
        finalize<<<BATCH / 4, 256, 0, stream>>>(Hpart, 4, fcb, g2, b2, m2, v2,
                                                fc2w, fc2b, bias, (float*)d_out);
    }
}